// Round 5
// baseline (493.005 us; speedup 1.0000x reference)
//
#include <hip/hip_runtime.h>
#include <stdint.h>

#define IN_F   4096
#define OUT_F  4096
#define M_TOT  8192   // 4 * 2048
#define BK     32
#define NT     (IN_F / BK)   // 128 K-tiles
#define BUF_B  32768         // bytes per LDS buffer: A 16K + B 16K
#define NBUF   4             // ring depth (128 KiB total, STATIC LDS)

typedef __bf16 bf16x8 __attribute__((ext_vector_type(8)));
typedef float  floatx4 __attribute__((ext_vector_type(4)));

// counted vmcnt wait: keeps newest N vmem ops in flight (T4)
#define WAITVM(N) asm volatile("s_waitcnt vmcnt(" #N ")" ::: "memory")
// drain own ds_reads; sched_barrier stops MFMA hoisting above it (rule #18)
#define LGKM0() do {                                   \
    asm volatile("s_waitcnt lgkmcnt(0)" ::: "memory"); \
    __builtin_amdgcn_sched_barrier(0);                 \
} while (0)
// raw barrier WITHOUT the compiler's implicit vmcnt(0) drain
#define FENCE_BARRIER() do {                          \
    asm volatile("" ::: "memory");                    \
    __builtin_amdgcn_s_barrier();                     \
    asm volatile("" ::: "memory");                    \
    __builtin_amdgcn_sched_barrier(0);                \
} while (0)

__device__ __forceinline__ unsigned short f2bf_bits(float f) {
    union { float f; uint32_t u; } v; v.f = f;
    uint32_t r = v.u + 0x7FFF + ((v.u >> 16) & 1);   // RNE
    return (unsigned short)(r >> 16);
}

__device__ __forceinline__ void gl_lds16(const void* g, void* l) {
    __builtin_amdgcn_global_load_lds(
        (const __attribute__((address_space(1))) void*)g,
        (__attribute__((address_space(3))) void*)l, 16, 0, 0);
}

// ---- x: fp32 -> bf16, 8 elements/thread (16B stores) — R3-verified ----
__global__ void cvt_x_kernel(const float* __restrict__ x, ushort* __restrict__ xb) {
    int i = blockIdx.x * blockDim.x + threadIdx.x;
    const float4* xp = reinterpret_cast<const float4*>(x);
    float4 a = xp[2 * i], b = xp[2 * i + 1];
    uint4 o;
    o.x = (uint32_t)f2bf_bits(a.x) | ((uint32_t)f2bf_bits(a.y) << 16);
    o.y = (uint32_t)f2bf_bits(a.z) | ((uint32_t)f2bf_bits(a.w) << 16);
    o.z = (uint32_t)f2bf_bits(b.x) | ((uint32_t)f2bf_bits(b.y) << 16);
    o.w = (uint32_t)f2bf_bits(b.z) | ((uint32_t)f2bf_bits(b.w) << 16);
    reinterpret_cast<uint4*>(xb)[i] = o;
}

// ---- W: packed int4 -> bf16, 4 packed (8 weights)/thread — R3-verified ----
__global__ void dequant_kernel(const int* __restrict__ packed,
                               const float* __restrict__ scales,
                               const float* __restrict__ offsets,
                               ushort* __restrict__ wb) {
    int i = blockIdx.x * blockDim.x + threadIdx.x;   // chunk of 4 packed ints
    int4 p = reinterpret_cast<const int4*>(packed)[i];
    int g = i >> 4;                                  // (8*i)/128
    float s = scales[g], off = offsets[g];
    uint4 ov;
    {
        int pv = p.x;
        unsigned w0 = f2bf_bits((float)(pv & 0xF) * s + off);
        unsigned w1 = f2bf_bits((float)((pv >> 4) & 0xF) * s + off);
        ov.x = w0 | (w1 << 16);
    }
    {
        int pv = p.y;
        unsigned w0 = f2bf_bits((float)(pv & 0xF) * s + off);
        unsigned w1 = f2bf_bits((float)((pv >> 4) & 0xF) * s + off);
        ov.y = w0 | (w1 << 16);
    }
    {
        int pv = p.z;
        unsigned w0 = f2bf_bits((float)(pv & 0xF) * s + off);
        unsigned w1 = f2bf_bits((float)((pv >> 4) & 0xF) * s + off);
        ov.z = w0 | (w1 << 16);
    }
    {
        int pv = p.w;
        unsigned w0 = f2bf_bits((float)(pv & 0xF) * s + off);
        unsigned w1 = f2bf_bits((float)((pv >> 4) & 0xF) * s + off);
        ov.w = w0 | (w1 << 16);
    }
    reinterpret_cast<uint4*>(wb)[i] = ov;
}

// ---- GEMM: C[M_TOT][OUT_F] = A[M_TOT][IN_F] * B[OUT_F][IN_F]^T + bias ----
// 256x256 tile, BK=32, 512 threads (2x4 waves, each 128x64 via 8x4 MFMA 16x16x32).
// Ring-4 STATIC-LDS (128 KiB), counted vmcnt (2 tiles of loads in flight over
// each barrier). Each K-tile split into 2 phases of 16 MFMA (m201
// granularity): Ph1 {8 ds_read (A0-3,B0-3) + 2 gl_lds (A-half of t+3) + bar +
// lgkm0 + 16 MFMA + bar}, Ph2 {4 ds_read (A4-7) + 2 gl_lds (B-half) +
// vmcnt(4) + bar + lgkm0 + 16 MFMA + bar}. Short phases keep the LDS and MFMA
// pipes concurrently fed across the 8 waves (setprio arbitrates).
// Ledger: top-of-iter outstanding = tile t+2 only => tile t fully landed;
// stage targets slot (t+3)&3 = (t-1)&3, whose last reads drained at iter t-1
// Ph2's lgkm0, >=2 barriers before the stage issues. Control flow is
// barrier-uniform (no conditional barriers).
__launch_bounds__(512, 2)
__global__ void gemm_kernel(const ushort* __restrict__ A,   // bf16 [M_TOT][IN_F]
                            const ushort* __restrict__ B,   // bf16 [OUT_F][IN_F]
                            const float* __restrict__ bias,
                            float* __restrict__ C) {
    __shared__ __align__(16) char smem[NBUF * BUF_B];   // 131072 B static LDS

    const int tid  = threadIdx.x;
    const int wave = tid >> 6;       // 0..7
    const int lane = tid & 63;
    const int quad = lane >> 4;      // 0..3
    const int l16  = lane & 15;
    const int wm   = wave >> 2;      // 0..1  (M)
    const int wn   = wave & 3;       // 0..3  (N)

    // XCD-chunked swizzle (bijective: 512 wgs, 8 XCDs, 64 wg/chunk)
    int id = blockIdx.y * gridDim.x + blockIdx.x;
    id = (id & 7) * 64 + (id >> 3);
    const int bn = id & 15;          // OUT_F/256 = 16
    const int bm = id >> 4;          // M_TOT/256 = 32

    // ---- staging source coords (per-lane, inverse-swizzled) ----
    // chunk c covers LDS 16B slot c of a 16 KiB half; row r = c>>2,
    // linear col-byte cb' = (c&3)*16, source col cb = cb' ^ swz(r)
    const int c0 = tid, c1 = 512 + tid;
    const int r0 = c0 >> 2, r1 = c1 >> 2;
    const int cb0 = ((c0 & 3) << 4) ^ (((r0 >> 1) & 3) << 4);
    const int cb1 = ((c1 & 3) << 4) ^ (((r1 >> 1) & 3) << 4);
    const ushort* gA0 = A + (size_t)(bm * 256 + r0) * IN_F + (cb0 >> 1);
    const ushort* gA1 = A + (size_t)(bm * 256 + r1) * IN_F + (cb1 >> 1);
    const ushort* gB0 = B + (size_t)(bn * 256 + r0) * IN_F + (cb0 >> 1);
    const ushort* gB1 = B + (size_t)(bn * 256 + r1) * IN_F + (cb1 >> 1);
    // wave-uniform LDS dest bases (HW adds lane*16)
    const int ldsA0 = wave * 1024;
    const int ldsA1 = 8192 + wave * 1024;
    const int ldsB0 = 16384 + wave * 1024;
    const int ldsB1 = 24576 + wave * 1024;

    auto STAGE_FULL = [&](int t) {
        char* base = smem + (t & (NBUF - 1)) * BUF_B;
        const int ko = t * BK;
        gl_lds16(gA0 + ko, base + ldsA0);
        gl_lds16(gA1 + ko, base + ldsA1);
        gl_lds16(gB0 + ko, base + ldsB0);
        gl_lds16(gB1 + ko, base + ldsB1);
    };
    auto STAGE_A = [&](int t) {
        char* base = smem + (t & (NBUF - 1)) * BUF_B;
        const int ko = t * BK;
        gl_lds16(gA0 + ko, base + ldsA0);
        gl_lds16(gA1 + ko, base + ldsA1);
    };
    auto STAGE_B = [&](int t) {
        char* base = smem + (t & (NBUF - 1)) * BUF_B;
        const int ko = t * BK;
        gl_lds16(gB0 + ko, base + ldsB0);
        gl_lds16(gB1 + ko, base + ldsB1);
    };

    // ---- read-side addressing (swizzled) ----
    // swz(row) invariant under row+16 -> compute once per thread
    const int arowb = wm * 128 + l16;
    const int browb = wn * 64 + l16;
    const int aswz = ((arowb >> 1) & 3) << 4;
    const int bswz = ((browb >> 1) & 3) << 4;
    const int acol = (((quad * 16) ^ aswz) >> 1);   // ushort offset in 32-wide row
    const int bcol = (((quad * 16) ^ bswz) >> 1);

    floatx4 acc[8][4] = {};
    bf16x8 a4[4], b4[4];

    auto READ_A = [&](const ushort* bufp, int mh) {    // A[mh*4 .. mh*4+3]
#pragma unroll
        for (int mi = 0; mi < 4; ++mi)
            a4[mi] = *reinterpret_cast<const bf16x8*>(
                bufp + (arowb + (mh * 4 + mi) * 16) * 32 + acol);
    };
    auto READ_B = [&](const ushort* bufp) {            // B[0..3]
#pragma unroll
        for (int ni = 0; ni < 4; ++ni)
            b4[ni] = *reinterpret_cast<const bf16x8*>(
                bufp + 8192 + (browb + ni * 16) * 32 + bcol);
    };

#define MFMA16(MH) do {                                              \
    __builtin_amdgcn_s_setprio(1);                                   \
    _Pragma("unroll")                                                \
    for (int mi = 0; mi < 4; ++mi)                                   \
        _Pragma("unroll")                                            \
        for (int ni = 0; ni < 4; ++ni)                               \
            acc[(MH) * 4 + mi][ni] =                                 \
                __builtin_amdgcn_mfma_f32_16x16x32_bf16(             \
                    a4[mi], b4[ni], acc[(MH) * 4 + mi][ni], 0, 0, 0);\
    __builtin_amdgcn_s_setprio(0);                                   \
} while (0)

    // ---- prologue: fill 3 ring slots; land tiles 0,1 (tile 2 in flight) ----
    STAGE_FULL(0); STAGE_FULL(1); STAGE_FULL(2);
    WAITVM(4);
    FENCE_BARRIER();

    // ---- main loop: 2 phases per K-tile, vmcnt counted once per tile ----
#pragma unroll 1
    for (int t = 0; t < NT - 3; ++t) {
        const ushort* bufp = (const ushort*)(smem + (t & (NBUF - 1)) * BUF_B);
        // Phase 1: mi 0-3
        READ_A(bufp, 0);
        READ_B(bufp);
        STAGE_A(t + 3);          // outstanding: t+2 (4) + 2 = 6
        FENCE_BARRIER();
        LGKM0();
        MFMA16(0);
        FENCE_BARRIER();
        // Phase 2: mi 4-7
        READ_A(bufp, 1);
        STAGE_B(t + 3);          // outstanding: 8
        WAITVM(4);               // drain tile t+2; t+3 stays in flight
        FENCE_BARRIER();
        LGKM0();
        MFMA16(1);
        FENCE_BARRIER();
    }

    // ---- tail: t = NT-3 (drain all), then NT-2, NT-1 (data resident) ----
    {
        const ushort* bufp = (const ushort*)(smem + ((NT - 3) & (NBUF - 1)) * BUF_B);
        READ_A(bufp, 0); READ_B(bufp);
        FENCE_BARRIER(); LGKM0(); MFMA16(0); FENCE_BARRIER();
        READ_A(bufp, 1);
        WAITVM(0);               // land tiles NT-2, NT-1
        FENCE_BARRIER(); LGKM0(); MFMA16(1); FENCE_BARRIER();
    }
#pragma unroll
    for (int t = NT - 2; t < NT; ++t) {
        const ushort* bufp = (const ushort*)(smem + (t & (NBUF - 1)) * BUF_B);
        READ_A(bufp, 0); READ_B(bufp);
        MFMA16(0);
        READ_A(bufp, 1);
        MFMA16(1);
    }
#undef MFMA16

    // ---- epilogue: D lane map col=l16, row=quad*4+r ----
    const int ccol = bn * 256 + wn * 64 + l16;
    const float* bp = bias + ccol;
    float* Cp = C + (size_t)(bm * 256 + wm * 128 + quad * 4) * OUT_F + ccol;
#pragma unroll
    for (int mi = 0; mi < 8; ++mi) {
#pragma unroll
        for (int ni = 0; ni < 4; ++ni) {
            float bv = bp[ni * 16];
#pragma unroll
            for (int r = 0; r < 4; ++r)
                Cp[(size_t)(mi * 16 + r) * OUT_F + ni * 16] = acc[mi][ni][r] + bv;
        }
    }
}

extern "C" void kernel_launch(void* const* d_in, const int* in_sizes, int n_in,
                              void* d_out, int out_size, void* d_ws, size_t ws_size,
                              hipStream_t stream) {
    const float* x       = (const float*)d_in[0];
    const int*   packed  = (const int*)d_in[1];
    const float* scales  = (const float*)d_in[2];
    const float* offsets = (const float*)d_in[3];
    const float* bias    = (const float*)d_in[4];
    float* out = (float*)d_out;

    ushort* xb = (ushort*)d_ws;                                     // 8192*4096*2 = 64 MiB
    ushort* wb = (ushort*)((char*)d_ws + (size_t)M_TOT * IN_F * 2); // 4096*4096*2 = 32 MiB

    // x: 33,554,432 elems / 8 per thread / 256 per block = 16384 blocks
    cvt_x_kernel<<<16384, 256, 0, stream>>>(x, xb);
    // packed: 8,388,608 elems / 4 per thread / 256 = 8192 blocks
    dequant_kernel<<<8192, 256, 0, stream>>>(packed, scales, offsets, wb);

    dim3 grid(OUT_F / 256, M_TOT / 256);   // (16, 32) = 512 wgs
    gemm_kernel<<<grid, 512, 0, stream>>>(xb, wb, bias, out);
}

// Round 6
// 484.401 us; speedup vs baseline: 1.0178x; 1.0178x over previous
//
#include <hip/hip_runtime.h>
#include <stdint.h>

#define IN_F   4096
#define OUT_F  4096
#define M_TOT  8192   // 4 * 2048
#define BK     64
#define NT2    (IN_F / BK)   // 64 K-tiles
#define HBUF   65536         // bytes per LDS buffer: A 32K + B 32K (2 bufs = 128 KiB)

typedef __bf16 bf16x8 __attribute__((ext_vector_type(8)));
typedef float  floatx4 __attribute__((ext_vector_type(4)));

// counted vmcnt wait: keeps newest N vmem ops in flight (T4)
#define WAITVM(N) asm volatile("s_waitcnt vmcnt(" #N ")" ::: "memory")
// drain own ds_reads; sched_barrier stops MFMA hoisting above it (rule #18)
#define LG() do {                                      \
    asm volatile("s_waitcnt lgkmcnt(0)" ::: "memory"); \
    __builtin_amdgcn_sched_barrier(0);                 \
} while (0)
// raw barrier WITHOUT the compiler's implicit vmcnt(0) drain
#define FB() do {                                     \
    asm volatile("" ::: "memory");                    \
    __builtin_amdgcn_s_barrier();                     \
    asm volatile("" ::: "memory");                    \
    __builtin_amdgcn_sched_barrier(0);                \
} while (0)

__device__ __forceinline__ unsigned short f2bf_bits(float f) {
    union { float f; uint32_t u; } v; v.f = f;
    uint32_t r = v.u + 0x7FFF + ((v.u >> 16) & 1);   // RNE
    return (unsigned short)(r >> 16);
}

__device__ __forceinline__ void gl_lds16(const void* g, void* l) {
    __builtin_amdgcn_global_load_lds(
        (const __attribute__((address_space(1))) void*)g,
        (__attribute__((address_space(3))) void*)l, 16, 0, 0);
}

// ---- x: fp32 -> bf16, 8 elements/thread (16B stores) — R3-verified ----
__global__ void cvt_x_kernel(const float* __restrict__ x, ushort* __restrict__ xb) {
    int i = blockIdx.x * blockDim.x + threadIdx.x;
    const float4* xp = reinterpret_cast<const float4*>(x);
    float4 a = xp[2 * i], b = xp[2 * i + 1];
    uint4 o;
    o.x = (uint32_t)f2bf_bits(a.x) | ((uint32_t)f2bf_bits(a.y) << 16);
    o.y = (uint32_t)f2bf_bits(a.z) | ((uint32_t)f2bf_bits(a.w) << 16);
    o.z = (uint32_t)f2bf_bits(b.x) | ((uint32_t)f2bf_bits(b.y) << 16);
    o.w = (uint32_t)f2bf_bits(b.z) | ((uint32_t)f2bf_bits(b.w) << 16);
    reinterpret_cast<uint4*>(xb)[i] = o;
}

// ---- W: packed int4 -> bf16, 4 packed (8 weights)/thread — R3-verified ----
__global__ void dequant_kernel(const int* __restrict__ packed,
                               const float* __restrict__ scales,
                               const float* __restrict__ offsets,
                               ushort* __restrict__ wb) {
    int i = blockIdx.x * blockDim.x + threadIdx.x;   // chunk of 4 packed ints
    int4 p = reinterpret_cast<const int4*>(packed)[i];
    int g = i >> 4;                                  // (8*i)/128
    float s = scales[g], off = offsets[g];
    uint4 ov;
    {
        int pv = p.x;
        unsigned w0 = f2bf_bits((float)(pv & 0xF) * s + off);
        unsigned w1 = f2bf_bits((float)((pv >> 4) & 0xF) * s + off);
        ov.x = w0 | (w1 << 16);
    }
    {
        int pv = p.y;
        unsigned w0 = f2bf_bits((float)(pv & 0xF) * s + off);
        unsigned w1 = f2bf_bits((float)((pv >> 4) & 0xF) * s + off);
        ov.y = w0 | (w1 << 16);
    }
    {
        int pv = p.z;
        unsigned w0 = f2bf_bits((float)(pv & 0xF) * s + off);
        unsigned w1 = f2bf_bits((float)((pv >> 4) & 0xF) * s + off);
        ov.z = w0 | (w1 << 16);
    }
    {
        int pv = p.w;
        unsigned w0 = f2bf_bits((float)(pv & 0xF) * s + off);
        unsigned w1 = f2bf_bits((float)((pv >> 4) & 0xF) * s + off);
        ov.w = w0 | (w1 << 16);
    }
    reinterpret_cast<uint4*>(wb)[i] = ov;
}

// ---- GEMM: C[M_TOT][OUT_F] = A[M_TOT][IN_F] * B[OUT_F][IN_F]^T + bias ----
// m201-faithful schedule: 256x256 tile, BK=64, 512 thr (2Mx4N waves, 128x64/wave).
// LDS: 2 dbuf x (A 32K + B 32K); each matrix tile = 2 K-half sub-blocks
// [256 rows][32 elems] with R2's verified zero-conflict XOR swizzle
// (byte_col ^= ((row>>1)&3)<<4; inverse-swizzled global source, linear
// gl_lds dest, swizzled ds_read — rule #21 both-sides).
// Per K-tile: 4 phases keyed (ks, nh), 16 MFMA each:
//   ph1: rd a(k0) 8 + b01(k0) 2 | stage Bk0(t+1) | bar lgkm0 MFMA bar
//   ph2: rd b23(k0) 2           | stage Ak0(t+1) | vmcnt(4) bar lgkm0 MFMA bar
//   ph3: rd a(k1) 8 + b01(k1) 2 | stage Bk1(t+1) | bar lgkm0 MFMA bar
//   ph4: rd b23(k1) 2           | stage Ak1(t+1) | vmcnt(4) bar lgkm0 MFMA bar
// Ledger (gl_lds ops/wave): entering ph1: outstanding = k1(t) 4 ops.
//   ph2's vmcnt(4) drains k1(t) (needed ph3), keeps k0(t+1).
//   ph4's vmcnt(4) drains k0(t+1) (needed next ph1), keeps k1(t+1). Invariant.
// Never vmcnt(0) in main loop; 4 ops in flight across every barrier.
__launch_bounds__(512, 2)
__global__ void gemm_kernel(const ushort* __restrict__ A,   // bf16 [M_TOT][IN_F]
                            const ushort* __restrict__ B,   // bf16 [OUT_F][IN_F]
                            const float* __restrict__ bias,
                            float* __restrict__ C) {
    __shared__ __align__(16) char smem[2 * HBUF];   // 131072 B static LDS

    const int tid  = threadIdx.x;
    const int wave = tid >> 6;       // 0..7
    const int lane = tid & 63;
    const int quad = lane >> 4;      // 0..3
    const int l16  = lane & 15;
    const int wm   = wave >> 2;      // 0..1  (M)
    const int wn   = wave & 3;       // 0..3  (N)

    // XCD-chunked swizzle (bijective: 512 wgs, 8 XCDs, 64 wg/chunk)
    int id = blockIdx.y * gridDim.x + blockIdx.x;
    id = (id & 7) * 64 + (id >> 3);
    const int bn = id & 15;          // OUT_F/256 = 16
    const int bm = id >> 4;          // M_TOT/256 = 32

    // ---- staging coords: sub-block = [256 rows][64 B]; chunk c = j*512+tid,
    // row = j*128 + (tid>>2), slot = tid&3; src col = slot*16 ^ ((row>>1)&3)<<4
    // ((row>>1)&3 is j-independent since j*128 ≡ 0 mod 8) ----
    const int rbase = tid >> 2;                                    // 0..127
    const int scol  = ((tid & 3) << 4) ^ (((rbase >> 1) & 3) << 4);
    const ushort* pA = A + (size_t)(bm * 256 + rbase) * IN_F + (scol >> 1);
    const ushort* pB = B + (size_t)(bn * 256 + rbase) * IN_F + (scol >> 1);
    const int ldsw = wave * 1024;    // HW adds lane*16

    auto STG = [&](const ushort* g, char* subblk, int eo) {  // one 16KiB sub-block
        gl_lds16(g + eo, subblk + ldsw);
        gl_lds16(g + eo + (size_t)128 * IN_F, subblk + 8192 + ldsw);
    };

    // ---- read-side (swizzled; (row>>1)&3 invariant under row+16) ----
    const int arow0 = wm * 128 + l16;
    const int brow0 = wn * 64 + l16;
    const int acol = (((quad << 4) ^ (((arow0 >> 1) & 3) << 4)) >> 1);
    const int bcol = (((quad << 4) ^ (((brow0 >> 1) & 3) << 4)) >> 1);

    floatx4 acc[8][4] = {};
    bf16x8 a8[8], bb[4];

    auto RDA = [&](const ushort* bufp, int ks) {
#pragma unroll
        for (int mi = 0; mi < 8; ++mi)
            a8[mi] = *reinterpret_cast<const bf16x8*>(
                bufp + ks * 8192 + (arow0 + mi * 16) * 32 + acol);
    };
    auto RDB = [&](const ushort* bufp, int ks, int nh) {
#pragma unroll
        for (int ni = 0; ni < 2; ++ni)
            bb[nh * 2 + ni] = *reinterpret_cast<const bf16x8*>(
                bufp + 16384 + ks * 8192 + (brow0 + (nh * 2 + ni) * 16) * 32 + bcol);
    };

#define MFMA16(NH) do {                                                   \
    __builtin_amdgcn_s_setprio(1);                                        \
    _Pragma("unroll")                                                     \
    for (int mi = 0; mi < 8; ++mi)                                        \
        _Pragma("unroll")                                                 \
        for (int ni = 0; ni < 2; ++ni)                                    \
            acc[mi][(NH) * 2 + ni] =                                      \
                __builtin_amdgcn_mfma_f32_16x16x32_bf16(                  \
                    a8[mi], bb[(NH) * 2 + ni], acc[mi][(NH) * 2 + ni],    \
                    0, 0, 0);                                             \
    __builtin_amdgcn_s_setprio(0);                                        \
} while (0)

#define TILE_MAIN(CB, SB, ts) do {                                        \
    const ushort* bp_ = (const ushort*)(smem + (CB));                     \
    char* aS_ = smem + (SB);                                              \
    char* bS_ = smem + (SB) + 32768;                                      \
    const int eo_ = (ts) * 64;                                            \
    RDA(bp_, 0); RDB(bp_, 0, 0); STG(pB, bS_, eo_);                       \
    FB(); LG(); MFMA16(0); FB();                                          \
    RDB(bp_, 0, 1); STG(pA, aS_, eo_); WAITVM(4);                         \
    FB(); LG(); MFMA16(1); FB();                                          \
    RDA(bp_, 1); RDB(bp_, 1, 0); STG(pB, bS_ + 16384, eo_ + 32);          \
    FB(); LG(); MFMA16(0); FB();                                          \
    RDB(bp_, 1, 1); STG(pA, aS_ + 16384, eo_ + 32); WAITVM(4);            \
    FB(); LG(); MFMA16(1); FB();                                          \
} while (0)

#define TILE_LAST(CB) do {                                                \
    const ushort* bp_ = (const ushort*)(smem + (CB));                     \
    RDA(bp_, 0); RDB(bp_, 0, 0); FB(); LG(); MFMA16(0); FB();             \
    RDB(bp_, 0, 1); WAITVM(0);   FB(); LG(); MFMA16(1); FB();             \
    RDA(bp_, 1); RDB(bp_, 1, 0); FB(); LG(); MFMA16(0); FB();             \
    RDB(bp_, 1, 1); LG(); MFMA16(1);                                      \
} while (0)

    // ---- prologue: tile 0 -> buf0 in need-order; keep k1(0) in flight ----
    STG(pB, smem + 32768, 0);            // B k0
    STG(pA, smem, 0);                    // A k0
    STG(pB, smem + 32768 + 16384, 32);   // B k1
    STG(pA, smem + 16384, 32);           // A k1
    WAITVM(4);                           // drain k0(0); k1(0) stays in flight
    FB();

    // ---- main loop: 2 K-tiles per iter (compile-time dbuf toggle) ----
#pragma unroll 1
    for (int t = 0; t < NT2 - 2; t += 2) {
        TILE_MAIN(0,    HBUF, t + 1);    // compute tile t   (buf0), stage t+1 -> buf1
        TILE_MAIN(HBUF, 0,    t + 2);    // compute tile t+1 (buf1), stage t+2 -> buf0
    }
    TILE_MAIN(0, HBUF, NT2 - 1);         // compute tile 62, stage 63 -> buf1
    TILE_LAST(HBUF);                     // compute tile 63, progressive drain

#undef TILE_MAIN
#undef TILE_LAST
#undef MFMA16

    // ---- epilogue: D lane map col=l16, row=quad*4+r ----
    const int ccol = bn * 256 + wn * 64 + l16;
    const float* bp = bias + ccol;
    float* Cp = C + (size_t)(bm * 256 + wm * 128 + quad * 4) * OUT_F + ccol;
#pragma unroll
    for (int mi = 0; mi < 8; ++mi) {
#pragma unroll
        for (int ni = 0; ni < 4; ++ni) {
            float bv = bp[ni * 16];
#pragma unroll
            for (int r = 0; r < 4; ++r)
                Cp[(size_t)(mi * 16 + r) * OUT_F + ni * 16] = acc[mi][ni][r] + bv;
        }
    }
}

extern "C" void kernel_launch(void* const* d_in, const int* in_sizes, int n_in,
                              void* d_out, int out_size, void* d_ws, size_t ws_size,
                              hipStream_t stream) {
    const float* x       = (const float*)d_in[0];
    const int*   packed  = (const int*)d_in[1];
    const float* scales  = (const float*)d_in[2];
    const float* offsets = (const float*)d_in[3];
    const float* bias    = (const float*)d_in[4];
    float* out = (float*)d_out;

    ushort* xb = (ushort*)d_ws;                                     // 8192*4096*2 = 64 MiB
    ushort* wb = (ushort*)((char*)d_ws + (size_t)M_TOT * IN_F * 2); // 4096*4096*2 = 32 MiB

    // x: 33,554,432 elems / 8 per thread / 256 per block = 16384 blocks
    cvt_x_kernel<<<16384, 256, 0, stream>>>(x, xb);
    // packed: 8,388,608 elems / 4 per thread / 256 = 8192 blocks
    dequant_kernel<<<8192, 256, 0, stream>>>(packed, scales, offsets, wb);

    dim3 grid(OUT_F / 256, M_TOT / 256);   // (16, 32) = 512 wgs
    gemm_kernel<<<grid, 512, 0, stream>>>(xb, wb, bias, out);
}